// Round 7
// baseline (70.431 us; speedup 1.0000x reference)
//
#include <hip/hip_runtime.h>
#include <math.h>

// Problem constants (from reference): x[B][L][D] fp32
#define B 8
#define L 4096
#define D 512
#define BLD ((size_t)B * L * D)

// v2 path: 2 channels per thread, LC2=32
#define LC2 32
#define CK2 (L / LC2)        // 128 chunks
#define HD (D / 2)           // 256 channel-pairs
#define WS2_FLOATS (2 * B * CK2 * D)   // 4 MiB

// v1 (round-6) path: 1 channel per thread, LC1=64
#define LC1 64
#define CK1 (L / LC1)        // 64
#define WS1_FLOATS (2 * B * CK1 * D)   // 2 MiB (proven available)

typedef float v2f __attribute__((ext_vector_type(2)));
typedef float v4f __attribute__((ext_vector_type(4)));

// phazor = exp(-|z|^2) * z/|z|   (no trig needed)
__device__ __forceinline__ v2f phazor_of(const float* __restrict__ pparam, int d) {
    float a = pparam[d * 2 + 0];
    float bb = pparam[d * 2 + 1];
    float r2 = fmaf(a, a, bb * bb);
    float inv = rsqrtf(r2);
    inv = inv * fmaf(-0.5f * r2 * inv, inv, 1.5f);   // Newton refinement
    float mag = __expf(-r2);
    v2f p; p.x = mag * a * inv; p.y = mag * bb * inv;
    return p;
}

// ---------------- v2 path: 2 channels/thread, LC=32 ----------------

__global__ __launch_bounds__(256) void pass1_v2(const float* __restrict__ x,
                                                const float* __restrict__ pparam,
                                                float* __restrict__ le) {
    int idx = blockIdx.x * blockDim.x + threadIdx.x;   // b*CK2*HD + c*HD + h
    int h = idx % HD;
    int c = (idx / HD) % CK2;
    int b = idx / (HD * CK2);
    int d0 = h * 2;
    v2f p0 = phazor_of(pparam, d0);
    v2f p1 = phazor_of(pparam, d0 + 1);
    float ur0 = 0.f, ui0 = 0.f, ur1 = 0.f, ui1 = 0.f;
    const float* xp = x + ((size_t)b * L + (size_t)c * LC2) * D + d0;
#pragma unroll 8
    for (int i = 0; i < LC2; ++i) {
        v2f xv = *(const v2f*)(xp + (size_t)i * D);
        float nr0 = fmaf(p0.x, ur0, fmaf(-p0.y, ui0, xv.x));
        float ni0 = fmaf(p0.x, ui0, p0.y * ur0);
        float nr1 = fmaf(p1.x, ur1, fmaf(-p1.y, ui1, xv.y));
        float ni1 = fmaf(p1.x, ui1, p1.y * ur1);
        ur0 = nr0; ui0 = ni0; ur1 = nr1; ui1 = ni1;
    }
    v4f lv; lv.x = ur0; lv.y = ui0; lv.z = ur1; lv.w = ui1;
    *(v4f*)(le + ((size_t)(b * CK2 + c) * D + d0) * 2) = lv;
}

template <int MODE>
__global__ __launch_bounds__(256) void pass2_v2(const float* __restrict__ x,
                                                const float* __restrict__ hr,
                                                const float* __restrict__ hi,
                                                const float* __restrict__ pinit,
                                                const float* __restrict__ pparam,
                                                const float* __restrict__ le,
                                                float* __restrict__ out) {
    int idx = blockIdx.x * blockDim.x + threadIdx.x;   // b*CK2*HD + c*HD + h
    int h = idx % HD;
    int c = (idx / HD) % CK2;     // uniform within a block (HD == blockDim)
    int b = idx / (HD * CK2);
    int d0 = h * 2;

    v2f p0 = phazor_of(pparam, d0);
    v2f p1 = phazor_of(pparam, d0 + 1);
    v2f q0 = *(const v2f*)(pinit + d0 * 2);
    v2f q1 = *(const v2f*)(pinit + d0 * 2 + 2);

    // P32 = phazor^LC2 via 5 complex squarings (per channel)
    float br0 = p0.x, bi0 = p0.y, br1 = p1.x, bi1 = p1.y;
#pragma unroll
    for (int s = 0; s < 5; ++s) {
        float s0r = fmaf(br0, br0, -bi0 * bi0), s0i = 2.f * br0 * bi0;
        float s1r = fmaf(br1, br1, -bi1 * bi1), s1i = 2.f * br1 * bi1;
        br0 = s0r; bi0 = s0i; br1 = s1r; bi1 = s1i;
    }

    // carry-in W[c] = sum_{j<c} P32^{c-1-j} * le[b][j][d]  (Horner, ascending j)
    float ur0 = 0.f, ui0 = 0.f, ur1 = 0.f, ui1 = 0.f;
    const float* lp = le + (((size_t)b * CK2) * D + d0) * 2;
    for (int j = 0; j < c; ++j) {
        v4f lv = *(const v4f*)(lp + (size_t)j * D * 2);
        float w0r = fmaf(ur0, br0, fmaf(-ui0, bi0, lv.x));
        float w0i = fmaf(ur0, bi0, fmaf(ui0, br0, lv.y));
        float w1r = fmaf(ur1, br1, fmaf(-ui1, bi1, lv.z));
        float w1i = fmaf(ur1, bi1, fmaf(ui1, br1, lv.w));
        ur0 = w0r; ui0 = w0i; ur1 = w1r; ui1 = w1i;
    }

    // pw = phazor^(c*LC2 + 1) = P32^c * phazor  (binary exp over 7 bits of c)
    float pw0r = p0.x, pw0i = p0.y, pw1r = p1.x, pw1i = p1.y;
    {
        float e0r = br0, e0i = bi0, e1r = br1, e1i = bi1;
        int n = c;
#pragma unroll
        for (int s = 0; s < 7; ++s) {
            if (n & 1) {
                float t0r = fmaf(pw0r, e0r, -pw0i * e0i);
                float t0i = fmaf(pw0r, e0i, pw0i * e0r);
                float t1r = fmaf(pw1r, e1r, -pw1i * e1i);
                float t1i = fmaf(pw1r, e1i, pw1i * e1r);
                pw0r = t0r; pw0i = t0i; pw1r = t1r; pw1i = t1i;
            }
            float s0r = fmaf(e0r, e0r, -e0i * e0i), s0i = 2.f * e0r * e0i;
            float s1r = fmaf(e1r, e1r, -e1i * e1i), s1i = 2.f * e1r * e1i;
            e0r = s0r; e0i = s0i; e1r = s1r; e1i = s1i;
            n >>= 1;
        }
    }

    v2f hre = *(const v2f*)(hr + (size_t)b * D + d0);
    v2f him = *(const v2f*)(hi + (size_t)b * D + d0);

    const float* xp = x + ((size_t)b * L + (size_t)c * LC2) * D + d0;
    float* outr = out + ((size_t)b * L + (size_t)c * LC2) * D + d0;
    float* outr2 = outr + BLD;
    float* outc = out + BLD + (((size_t)b * L + (size_t)c * LC2) * D + d0) * 2;

#pragma unroll 4
    for (int i = 0; i < LC2; ++i) {
        v2f xv = *(const v2f*)(xp + (size_t)i * D);
        float nr0 = fmaf(p0.x, ur0, fmaf(-p0.y, ui0, xv.x));
        float ni0 = fmaf(p0.x, ui0, p0.y * ur0);
        float nr1 = fmaf(p1.x, ur1, fmaf(-p1.y, ui1, xv.y));
        float ni1 = fmaf(p1.x, ui1, p1.y * ur1);
        ur0 = nr0; ui0 = ni0; ur1 = nr1; ui1 = ni1;
        float vr0 = fmaf(q0.x, ur0, fmaf(-q0.y, ui0, fmaf(hre.x, pw0r, -him.x * pw0i)));
        float vi0 = fmaf(q0.x, ui0, fmaf(q0.y, ur0, fmaf(hre.x, pw0i, him.x * pw0r)));
        float vr1 = fmaf(q1.x, ur1, fmaf(-q1.y, ui1, fmaf(hre.y, pw1r, -him.y * pw1i)));
        float vi1 = fmaf(q1.x, ui1, fmaf(q1.y, ur1, fmaf(hre.y, pw1i, him.y * pw1r)));
        v2f vv; vv.x = vr0; vv.y = vr1;
        *(v2f*)(outr + (size_t)i * D) = vv;
        if (MODE == 0) {
            *(v2f*)(outr2 + (size_t)i * D) = vv;
        } else {
            v4f vc; vc.x = vr0; vc.y = vi0; vc.z = vr1; vc.w = vi1;
            *(v4f*)(outc + (size_t)i * D * 2) = vc;
        }
        float t0r = fmaf(pw0r, p0.x, -pw0i * p0.y);
        float t0i = fmaf(pw0r, p0.y, pw0i * p0.x);
        float t1r = fmaf(pw1r, p1.x, -pw1i * p1.y);
        float t1i = fmaf(pw1r, p1.y, pw1i * p1.x);
        pw0r = t0r; pw0i = t0i; pw1r = t1r; pw1i = t1i;
    }
}

// ---------------- v1 path (round-6, proven): 1 channel/thread, LC=64 --------

__global__ __launch_bounds__(256) void pass1_k(const float* __restrict__ x,
                                               const float* __restrict__ pparam,
                                               float* __restrict__ le) {
    int idx = blockIdx.x * blockDim.x + threadIdx.x;
    int d = idx % D;
    v2f ph = phazor_of(pparam, d);
    int c = (idx / D) % CK1;
    int b = idx / (D * CK1);
    float ur = 0.f, ui = 0.f;
    const float* xp = x + ((size_t)b * L + (size_t)c * LC1) * D + d;
#pragma unroll 8
    for (int i = 0; i < LC1; ++i) {
        float xv = xp[(size_t)i * D];
        float nr = fmaf(ph.x, ur, fmaf(-ph.y, ui, xv));
        float ni = fmaf(ph.x, ui, ph.y * ur);
        ur = nr; ui = ni;
    }
    v2f lv; lv.x = ur; lv.y = ui;
    *(v2f*)(le + (size_t)idx * 2) = lv;
}

template <int MODE>
__global__ __launch_bounds__(256) void pass2_k(const float* __restrict__ x,
                                               const float* __restrict__ hr,
                                               const float* __restrict__ hi,
                                               const float* __restrict__ pinit,
                                               const float* __restrict__ pparam,
                                               const float* __restrict__ le,
                                               float* __restrict__ out) {
    int idx = blockIdx.x * blockDim.x + threadIdx.x;
    int d = idx % D;
    int c = (idx / D) % CK1;
    int b = idx / (D * CK1);
    v2f ph = phazor_of(pparam, d);
    v2f q;  q.x = pinit[d * 2 + 0]; q.y = pinit[d * 2 + 1];
    float br = ph.x, bi = ph.y;
#pragma unroll
    for (int s = 0; s < 6; ++s) {
        float sr = fmaf(br, br, -bi * bi);
        float si = 2.f * br * bi;
        br = sr; bi = si;
    }
    float ur = 0.f, ui = 0.f;
    const float* lp = le + (((size_t)b * CK1) * D + d) * 2;
    for (int j = 0; j < c; ++j) {
        v2f lv = *(const v2f*)(lp + (size_t)j * D * 2);
        float wr = fmaf(ur, br, fmaf(-ui, bi, lv.x));
        float wi = fmaf(ur, bi, fmaf(ui, br, lv.y));
        ur = wr; ui = wi;
    }
    float pwr = ph.x, pwi = ph.y;
    {
        float er = br, ei = bi;
        int n = c;
#pragma unroll
        for (int s = 0; s < 6; ++s) {
            if (n & 1) {
                float tr = fmaf(pwr, er, -pwi * ei);
                float ti = fmaf(pwr, ei, pwi * er);
                pwr = tr; pwi = ti;
            }
            float sr = fmaf(er, er, -ei * ei);
            float si = 2.f * er * ei;
            er = sr; ei = si;
            n >>= 1;
        }
    }
    float hre = hr[(size_t)b * D + d];
    float him = hi[(size_t)b * D + d];
    const float* xp = x + ((size_t)b * L + (size_t)c * LC1) * D + d;
    float* outr = out + ((size_t)b * L + (size_t)c * LC1) * D + d;
    float* outr2 = outr + BLD;
    float* outc = out + BLD + (((size_t)b * L + (size_t)c * LC1) * D + d) * 2;
#pragma unroll 4
    for (int i = 0; i < LC1; ++i) {
        float xv = xp[(size_t)i * D];
        float nr = fmaf(ph.x, ur, fmaf(-ph.y, ui, xv));
        float ni = fmaf(ph.x, ui, ph.y * ur);
        ur = nr; ui = ni;
        float vr = fmaf(q.x, ur, fmaf(-q.y, ui, fmaf(hre, pwr, -him * pwi)));
        float vi = fmaf(q.x, ui, fmaf(q.y, ur, fmaf(hre, pwi, him * pwr)));
        outr[(size_t)i * D] = vr;
        if (MODE == 0) {
            outr2[(size_t)i * D] = vr;
        } else {
            v2f vc; vc.x = vr; vc.y = vi;
            *(v2f*)(outc + (size_t)i * D * 2) = vc;
        }
        float tr = fmaf(pwr, ph.x, -pwi * ph.y);
        float ti = fmaf(pwr, ph.y, pwi * ph.x);
        pwr = tr; pwi = ti;
    }
}

// ---------------- serial fallback (no scratch) ----------------

template <int MODE>
__global__ __launch_bounds__(256) void fallback_k(const float* __restrict__ x,
                                                  const float* __restrict__ hr,
                                                  const float* __restrict__ hi,
                                                  const float* __restrict__ pinit,
                                                  const float* __restrict__ pparam,
                                                  float* __restrict__ out) {
    int idx = blockIdx.x * blockDim.x + threadIdx.x;
    if (idx >= B * D) return;
    int d = idx % D;
    int b = idx / D;
    v2f ph = phazor_of(pparam, d);
    float qr = pinit[d * 2 + 0];
    float qi = pinit[d * 2 + 1];
    float hre = hr[(size_t)b * D + d];
    float him = hi[(size_t)b * D + d];
    float ur = 0.f, ui = 0.f;
    float pwr = ph.x, pwi = ph.y;
    const float* xp = x + (size_t)b * L * D + d;
    float* outr = out + (size_t)b * L * D + d;
    float* outr2 = outr + BLD;
    float* outc = out + BLD + ((size_t)b * L * D + d) * 2;
    for (int t = 0; t < L; ++t) {
        float xv = xp[(size_t)t * D];
        float nr = fmaf(ph.x, ur, fmaf(-ph.y, ui, xv));
        float ni = fmaf(ph.x, ui, ph.y * ur);
        ur = nr; ui = ni;
        float vr = fmaf(qr, ur, fmaf(-qi, ui, fmaf(hre, pwr, -him * pwi)));
        float vi = fmaf(qr, ui, fmaf(qi, ur, fmaf(hre, pwi, him * pwr)));
        outr[(size_t)t * D] = vr;
        if (MODE == 0) {
            outr2[(size_t)t * D] = vr;
        } else {
            v2f vc; vc.x = vr; vc.y = vi;
            *(v2f*)(outc + (size_t)t * D * 2) = vc;
        }
        float tr = fmaf(pwr, ph.x, -pwi * ph.y);
        float ti = fmaf(pwr, ph.y, pwi * ph.x);
        pwr = tr; pwi = ti;
    }
}

extern "C" void kernel_launch(void* const* d_in, const int* in_sizes, int n_in,
                              void* d_out, int out_size, void* d_ws, size_t ws_size,
                              hipStream_t stream) {
    const float* x = (const float*)d_in[0];
    const float* hreal = (const float*)d_in[1];
    const float* himag = (const float*)d_in[2];
    const float* pinit = (const float*)d_in[3];
    const float* pparam = (const float*)d_in[4];
    float* le = (float*)d_ws;
    float* out = (float*)d_out;

    const int mode = (out_size >= (int)(3 * BLD)) ? 1 : 0;

    if (ws_size >= (size_t)WS2_FLOATS * sizeof(float)) {
        int n = B * CK2 * HD;                     // 262144 threads -> 4 waves/SIMD
        pass1_v2<<<n / 256, 256, 0, stream>>>(x, pparam, le);
        if (mode == 0)
            pass2_v2<0><<<n / 256, 256, 0, stream>>>(x, hreal, himag, pinit, pparam, le, out);
        else
            pass2_v2<1><<<n / 256, 256, 0, stream>>>(x, hreal, himag, pinit, pparam, le, out);
    } else if (ws_size >= (size_t)WS1_FLOATS * sizeof(float)) {
        int n = B * CK1 * D;                      // 262144 threads
        pass1_k<<<n / 256, 256, 0, stream>>>(x, pparam, le);
        if (mode == 0)
            pass2_k<0><<<n / 256, 256, 0, stream>>>(x, hreal, himag, pinit, pparam, le, out);
        else
            pass2_k<1><<<n / 256, 256, 0, stream>>>(x, hreal, himag, pinit, pparam, le, out);
    } else {
        int n = B * D;
        if (mode == 0)
            fallback_k<0><<<(n + 255) / 256, 256, 0, stream>>>(x, hreal, himag, pinit, pparam, out);
        else
            fallback_k<1><<<(n + 255) / 256, 256, 0, stream>>>(x, hreal, himag, pinit, pparam, out);
    }
}